// Round 13
// baseline (56.080 us; speedup 1.0000x reference)
//
#include <hip/hip_runtime.h>
#include <hip/hip_bf16.h>

// Problem constants
#define NB    65536      // batch rows
#define ND    1024       // feature dim (K)
#define NT    64         // trees (N)
#define BK    128        // K-chunk in floats (512B/row/phase; 8 phases)
#define NCH   (ND / BK)  // 8 chunks
#define ROWS  64         // rows per block (4 waves; wave w owns trees [16w,16w+16))

typedef __attribute__((ext_vector_type(8))) short bf16x8;
typedef __attribute__((ext_vector_type(4))) short bf16x4;
typedef __attribute__((ext_vector_type(4))) float f32x4;

__device__ __forceinline__ short f2bf_s(float f) {
    __hip_bfloat16 h = __float2bfloat16(f);
    return __builtin_bit_cast(short, h);
}

// lgkm-only barrier (no vmcnt drain) — proven correct R6-R12.
__device__ __forceinline__ void phase_barrier() {
    asm volatile("s_waitcnt lgkmcnt(0)\n\ts_barrier" ::: "memory");
}

// R12 structure at BK=128, VGPR-capped: single rA staging buffer (depth-1 A
// prefetch; phase >> HBM latency so depth-1 suffices), double rB. FIFO
// invariant kept: per phase, load_chunk issues BEFORE loadB, so the counted
// vmcnt wait in stage_write (for rA, 1 phase old) never drains B loads, and
// compute's B regs are >= 2 phases old (no wait at all).
__global__ __launch_bounds__(256, 4) void node_main(const float* __restrict__ x,
                                                    const float* __restrict__ F,
                                                    const float* __restrict__ thr,
                                                    const float* __restrict__ lw,
                                                    float* __restrict__ out) {
    __shared__ __align__(16) __hip_bfloat16 Abuf[2][ROWS * BK];   // 2 x 16 KB

    const int tid  = threadIdx.x;
    const int w    = tid >> 6;
    const int lane = tid & 63;
    const int c    = lane & 15;     // MFMA 16-index: batch row (A) / tree col (B)
    const int g    = lane >> 4;     // k-group
    const int rot  = blockIdx.x & (NCH - 1);   // per-block K-schedule rotation (kept, free)
    const long blockRow = (long)blockIdx.x * ROWS;
    const float* xbase = x + blockRow * ND;

    // staging: instruction (i,h) covers rows i*16 + srow, 16 lanes x 16B = 256B
    // contiguous per row-half; two halves h -> 512B per row per phase.
    const int srow = tid >> 4;      // 0..15
    const int scol = tid & 15;      // f32x4 granule within 256B half

    // per-lane tree constants (one tree per lane within the wave's 16-tree tile)
    const int   t     = w * 16 + c;
    const float thr_t = thr[t];
    const float w00 = lw[t * 4 + 0], w01 = lw[t * 4 + 1];
    const float w10 = lw[t * 4 + 2], w11 = lw[t * 4 + 3];
    const float* Ffrow = F + (long)t * ND;   // f32 B row, L2-resident

    f32x4 acc[4];
#pragma unroll
    for (int rt = 0; rt < 4; ++rt) acc[rt] = (f32x4){0.f, 0.f, 0.f, 0.f};

    f32x4  rA[8];            // single A staging buffer (32 VGPR)
    bf16x8 rB0[4], rB1[4];   // B fragment regs, double-buffered (32 VGPR)

    auto chmap = [&](int ch) { return (ch + rot) & (NCH - 1); };

    auto load_chunk = [&](int ch) {
        const int cm = chmap(ch);
#pragma unroll
        for (int i = 0; i < 4; ++i)
#pragma unroll
            for (int h = 0; h < 2; ++h) {
                const int r = i * 16 + srow;
                rA[i * 2 + h] = *(const f32x4*)(xbase + (long)r * ND + cm * BK + (scol + 16 * h) * 4);
            }
    };
    auto loadB = [&](int ch, bf16x8* rB) {
        const int cm = chmap(ch);
#pragma unroll
        for (int kk = 0; kk < 4; ++kk) {
            const float* fp = Ffrow + cm * BK + kk * 32 + g * 8;
            f32x4 b0 = *(const f32x4*)(fp);
            f32x4 b1 = *(const f32x4*)(fp + 4);
            bf16x8 bf;
            bf[0] = f2bf_s(b0[0]); bf[1] = f2bf_s(b0[1]);
            bf[2] = f2bf_s(b0[2]); bf[3] = f2bf_s(b0[3]);
            bf[4] = f2bf_s(b1[0]); bf[5] = f2bf_s(b1[1]);
            bf[6] = f2bf_s(b1[2]); bf[7] = f2bf_s(b1[3]);
            rB[kk] = bf;
        }
    };
    auto stage_write = [&](int buf) {
#pragma unroll
        for (int i = 0; i < 4; ++i)
#pragma unroll
            for (int h = 0; h < 2; ++h) {
                const int r  = i * 16 + srow;
                const int g8 = scol + 16 * h;            // 8B granule index, 0..31
                f32x4 a = rA[i * 2 + h];
                bf16x4 v;
                v[0] = f2bf_s(a[0]); v[1] = f2bf_s(a[1]);
                v[2] = f2bf_s(a[2]); v[3] = f2bf_s(a[3]);
                const int slot = (g8 >> 1) ^ (r & 7);    // 16B slot 0..15, XOR swizzle
                char* p = (char*)(&Abuf[buf][0]) + r * 256 + (slot << 4) + ((g8 & 1) << 3);
                *(bf16x4*)p = v;
            }
    };
    auto compute = [&](int buf, const bf16x8* rB) {
#pragma unroll
        for (int kk = 0; kk < 4; ++kk) {
#pragma unroll
            for (int rt = 0; rt < 4; ++rt) {
                const int r    = rt * 16 + c;
                const int slot = (kk * 4 + g) ^ (r & 7);
                bf16x8 afrag = *(const bf16x8*)((const char*)(&Abuf[buf][0]) + r * 256 + (slot << 4));
                acc[rt] = __builtin_amdgcn_mfma_f32_16x16x32_bf16(afrag, rB[kk], acc[rt], 0, 0, 0);
            }
        }
    };

    // prologue: stage chunk 0; chunk 1 A+B in flight
    load_chunk(0);
    loadB(0, rB0);
    stage_write(0);          // drains chunk-0 A loads (prologue only)
    load_chunk(1);
    loadB(1, rB1);
    phase_barrier();

#pragma unroll
    for (int p = 0; p < NCH; ++p) {
        const int cur = p & 1;                    // compile-time (full unroll)
        compute(cur, cur ? rB1 : rB0);            // B >= 2 phases old: no vm wait
        if (p + 1 < NCH) stage_write(cur ^ 1);    // rA = chunk p+1, 1 phase old
        if (p + 2 < NCH) {
            load_chunk(p + 2);                    // A first (FIFO: older than B)
            loadB(p + 2, cur ? rB1 : rB0);        // refill after compute used it
        }
        phase_barrier();
    }

    // ---- epilogue: sigmoid + leaf combine + tree reduction (proven R6) ----
    float* partials = (float*)(&Abuf[0][0]);   // aliased; safe after last phase_barrier
#pragma unroll
    for (int rt = 0; rt < 4; ++rt) {
#pragma unroll
        for (int reg = 0; reg < 4; ++reg) {
            const float logit = acc[rt][reg] - thr_t;
            const float p = 1.0f / (1.0f + __expf(-logit));
            float o0 = w10 + p * (w00 - w10);
            float o1 = w11 + p * (w01 - w11);
#pragma unroll
            for (int m = 1; m < 16; m <<= 1) {   // butterfly over 16 trees (c bits)
                o0 += __shfl_xor(o0, m, 64);
                o1 += __shfl_xor(o1, m, 64);
            }
            if (c == 0) {
                const int row = rt * 16 + g * 4 + reg;
                partials[(w * ROWS + row) * 2 + 0] = o0;
                partials[(w * ROWS + row) * 2 + 1] = o1;
            }
        }
    }
    __syncthreads();
    if (tid < 128) {
        const int row = tid >> 1, o = tid & 1;
        const float s = partials[(0 * ROWS + row) * 2 + o] + partials[(1 * ROWS + row) * 2 + o] +
                        partials[(2 * ROWS + row) * 2 + o] + partials[(3 * ROWS + row) * 2 + o];
        out[(blockRow + row) * 2 + o] = s;
    }
}

extern "C" void kernel_launch(void* const* d_in, const int* in_sizes, int n_in,
                              void* d_out, int out_size, void* d_ws, size_t ws_size,
                              hipStream_t stream) {
    const float* x   = (const float*)d_in[0];
    const float* fs  = (const float*)d_in[1];
    const float* thr = (const float*)d_in[2];
    const float* lw  = (const float*)d_in[3];
    float* out = (float*)d_out;
    (void)in_sizes; (void)n_in; (void)out_size; (void)d_ws; (void)ws_size;

    node_main<<<NB / ROWS, 256, 0, stream>>>(x, fs, thr, lw, out);
}

// Round 14
// 49.293 us; speedup vs baseline: 1.1377x; 1.1377x over previous
//
#include <hip/hip_runtime.h>
#include <hip/hip_bf16.h>

// Problem constants
#define NB    65536      // batch rows
#define ND    1024       // feature dim (K)
#define NT    64         // trees (N)
#define BK    64         // K-chunk in floats
#define NCH   (ND / BK)  // 16 chunks
#define ROWS  64         // rows per block (4 waves; wave w owns trees [16w,16w+16))

typedef __attribute__((ext_vector_type(8))) short bf16x8;
typedef __attribute__((ext_vector_type(4))) short bf16x4;
typedef __attribute__((ext_vector_type(4))) float f32x4;

__device__ __forceinline__ short f2bf_s(float f) {
    __hip_bfloat16 h = __float2bfloat16(f);
    return __builtin_bit_cast(short, h);
}

// lgkm-only barrier (no vmcnt drain) — proven correct R6-R12.
__device__ __forceinline__ void phase_barrier() {
    asm volatile("s_waitcnt lgkmcnt(0)\n\ts_barrier" ::: "memory");
}

// R12 (best: 49.29 us, ~5.45 TB/s): single kernel, B as f32 from L2 with
// inline cvt. LDS-staged A (XOR-swizzled, double-buffered), 2-phase-deep A
// register staging, 1-phase-deep B register staging so counted vmcnt waits
// never drain in-flight A HBM loads, per-block K-chunk rotation.
__global__ __launch_bounds__(256, 4) void node_main(const float* __restrict__ x,
                                                    const float* __restrict__ F,
                                                    const float* __restrict__ thr,
                                                    const float* __restrict__ lw,
                                                    float* __restrict__ out) {
    __shared__ __align__(16) __hip_bfloat16 Abuf[2][ROWS * BK];   // 2 x 8 KB

    const int tid  = threadIdx.x;
    const int w    = tid >> 6;
    const int lane = tid & 63;
    const int c    = lane & 15;     // MFMA 16-index: batch row (A) / tree col (B)
    const int g    = lane >> 4;     // k-group
    const int rot  = blockIdx.x & (NCH - 1);   // per-block K-schedule rotation
    const long blockRow = (long)blockIdx.x * ROWS;
    const float* xbase = x + blockRow * ND;

    // staging: pass i covers rows i*16 + srow; 16 lanes x 16B = 256B contiguous per row
    const int srow = tid >> 4;      // 0..15
    const int scol = tid & 15;      // f32x4 granule within row-chunk

    // per-lane tree constants (one tree per lane within the wave's 16-tree tile)
    const int   t     = w * 16 + c;
    const float thr_t = thr[t];
    const float w00 = lw[t * 4 + 0], w01 = lw[t * 4 + 1];
    const float w10 = lw[t * 4 + 2], w11 = lw[t * 4 + 3];
    const float* Ffrow = F + (long)t * ND;   // f32 B row, L2-resident

    f32x4 acc[4];
#pragma unroll
    for (int rt = 0; rt < 4; ++rt) acc[rt] = (f32x4){0.f, 0.f, 0.f, 0.f};

    f32x4  rA0[4], rA1[4];   // A chunk staging regs (2 phases deep)
    bf16x8 rB0[2], rB1[2];   // B fragment regs (1 phase deep)

    auto chmap = [&](int ch) { return (ch + rot) & (NCH - 1); };

    auto load_chunk = [&](int ch, f32x4* rA) {
        const int cm = chmap(ch);
#pragma unroll
        for (int i = 0; i < 4; ++i) {
            const int r = i * 16 + srow;
            rA[i] = *(const f32x4*)(xbase + (long)r * ND + cm * BK + scol * 4);
        }
    };
    auto loadB = [&](int ch, bf16x8* rB) {
        const int cm = chmap(ch);
#pragma unroll
        for (int kk = 0; kk < 2; ++kk) {
            const float* fp = Ffrow + cm * BK + kk * 32 + g * 8;
            f32x4 b0 = *(const f32x4*)(fp);
            f32x4 b1 = *(const f32x4*)(fp + 4);
            bf16x8 bf;
            bf[0] = f2bf_s(b0[0]); bf[1] = f2bf_s(b0[1]);
            bf[2] = f2bf_s(b0[2]); bf[3] = f2bf_s(b0[3]);
            bf[4] = f2bf_s(b1[0]); bf[5] = f2bf_s(b1[1]);
            bf[6] = f2bf_s(b1[2]); bf[7] = f2bf_s(b1[3]);
            rB[kk] = bf;
        }
    };
    auto stage_write = [&](int buf, const f32x4* rA) {
#pragma unroll
        for (int i = 0; i < 4; ++i) {
            const int r = i * 16 + srow;
            f32x4 a = rA[i];
            bf16x4 v;
            v[0] = f2bf_s(a[0]); v[1] = f2bf_s(a[1]);
            v[2] = f2bf_s(a[2]); v[3] = f2bf_s(a[3]);
            const int s = (scol >> 1) ^ (r & 7);      // T2 XOR swizzle, 16B slots
            char* p = (char*)(&Abuf[buf][0]) + r * 128 + (s << 4) + ((scol & 1) << 3);
            *(bf16x4*)p = v;
        }
    };
    auto compute = [&](int buf, const bf16x8* rB) {
#pragma unroll
        for (int kk = 0; kk < 2; ++kk) {
#pragma unroll
            for (int rt = 0; rt < 4; ++rt) {
                const int r    = rt * 16 + c;
                const int slot = (kk * 4 + g) ^ (r & 7);
                bf16x8 afrag = *(const bf16x8*)(&Abuf[buf][r * BK + slot * 8]);
                acc[rt] = __builtin_amdgcn_mfma_f32_16x16x32_bf16(afrag, rB[kk], acc[rt], 0, 0, 0);
            }
        }
    };

    // prologue: A chunks 0,1 and B fragments 0,1 in flight; stage 0
    load_chunk(0, rA0);
    load_chunk(1, rA1);
    loadB(0, rB0);
    loadB(1, rB1);
    stage_write(0, rA0);
    phase_barrier();

#pragma unroll
    for (int ch2 = 0; ch2 < NCH; ch2 += 2) {
        // ---- even phase: buf0 holds ch2, rB0 holds B(ch2) ----
        if (ch2 + 2 < NCH) load_chunk(ch2 + 2, rA0);
        compute(0, rB0);                         // waits only on phase-old loads
        if (ch2 + 2 < NCH) loadB(ch2 + 2, rB0);  // refill AFTER use; lands next phase
        stage_write(1, rA1);                     // rA1 loaded a full phase ago
        phase_barrier();
        // ---- odd phase: buf1 holds ch2+1, rB1 holds B(ch2+1) ----
        if (ch2 + 3 < NCH) load_chunk(ch2 + 3, rA1);
        compute(1, rB1);
        if (ch2 + 3 < NCH) loadB(ch2 + 3, rB1);
        if (ch2 + 2 < NCH) stage_write(0, rA0);
        phase_barrier();
    }

    // ---- epilogue: sigmoid + leaf combine + tree reduction (proven R6) ----
    float* partials = (float*)(&Abuf[0][0]);   // aliased; safe after last phase_barrier
#pragma unroll
    for (int rt = 0; rt < 4; ++rt) {
#pragma unroll
        for (int reg = 0; reg < 4; ++reg) {
            const float logit = acc[rt][reg] - thr_t;
            const float p = 1.0f / (1.0f + __expf(-logit));
            float o0 = w10 + p * (w00 - w10);
            float o1 = w11 + p * (w01 - w11);
#pragma unroll
            for (int m = 1; m < 16; m <<= 1) {   // butterfly over 16 trees (c bits)
                o0 += __shfl_xor(o0, m, 64);
                o1 += __shfl_xor(o1, m, 64);
            }
            if (c == 0) {
                const int row = rt * 16 + g * 4 + reg;
                partials[(w * ROWS + row) * 2 + 0] = o0;
                partials[(w * ROWS + row) * 2 + 1] = o1;
            }
        }
    }
    __syncthreads();
    if (tid < 128) {
        const int row = tid >> 1, o = tid & 1;
        const float s = partials[(0 * ROWS + row) * 2 + o] + partials[(1 * ROWS + row) * 2 + o] +
                        partials[(2 * ROWS + row) * 2 + o] + partials[(3 * ROWS + row) * 2 + o];
        out[(blockRow + row) * 2 + o] = s;
    }
}

extern "C" void kernel_launch(void* const* d_in, const int* in_sizes, int n_in,
                              void* d_out, int out_size, void* d_ws, size_t ws_size,
                              hipStream_t stream) {
    const float* x   = (const float*)d_in[0];
    const float* fs  = (const float*)d_in[1];
    const float* thr = (const float*)d_in[2];
    const float* lw  = (const float*)d_in[3];
    float* out = (float*)d_out;
    (void)in_sizes; (void)n_in; (void)out_size; (void)d_ws; (void)ws_size;

    node_main<<<NB / ROWS, 256, 0, stream>>>(x, fs, thr, lw, out);
}